// Round 1
// baseline (2796.169 us; speedup 1.0000x reference)
//
#include <hip/hip_runtime.h>
#include <math.h>

#define NN 50000
#define NE 500000
#define DD 128
#define EPSV 1e-12f

// ---------------- Kernel 1: node precompute ----------------
// As = x@Wsrc + P + bpos ; Ad = x@Wdst + P ; Xc = x@W - P ; P = pos@Wpos
__global__ __launch_bounds__(256) void node_precompute(
    const float* __restrict__ x, const float* __restrict__ pos,
    const float* __restrict__ W, const float* __restrict__ Wsrc,
    const float* __restrict__ Wdst, const float* __restrict__ Wpos,
    const float* __restrict__ bpos,
    float* __restrict__ As, float* __restrict__ Ad, float* __restrict__ Xc)
{
    __shared__ float xsT[128 * 32]; // [k][m], transposed x tile
    const int t = threadIdx.x;
    const int n0 = blockIdx.x * 32;
    const int jg = t & 31, mg = t >> 5;
    const int j0 = jg * 4, m0 = mg * 4;

    for (int idx = t; idx < 32 * 128; idx += 256) {
        int i = idx >> 7, k = idx & 127;
        int node = n0 + i;
        xsT[k * 32 + i] = (node < NN) ? x[node * 128 + k] : 0.0f;
    }
    __syncthreads();

    float wp[3][4];
#pragma unroll
    for (int d = 0; d < 3; ++d) {
        float4 w4 = *(const float4*)&Wpos[d * 128 + j0];
        wp[d][0] = w4.x; wp[d][1] = w4.y; wp[d][2] = w4.z; wp[d][3] = w4.w;
    }
    float4 bp4 = *(const float4*)&bpos[j0];
    float bp[4] = {bp4.x, bp4.y, bp4.z, bp4.w};
    float p[4][4];
#pragma unroll
    for (int u = 0; u < 4; ++u) {
        int node = n0 + m0 + u;
        float pd0 = 0.f, pd1 = 0.f, pd2 = 0.f;
        if (node < NN) { pd0 = pos[node * 3]; pd1 = pos[node * 3 + 1]; pd2 = pos[node * 3 + 2]; }
#pragma unroll
        for (int v = 0; v < 4; ++v)
            p[u][v] = pd0 * wp[0][v] + pd1 * wp[1][v] + pd2 * wp[2][v];
    }

#pragma unroll 1
    for (int w = 0; w < 3; ++w) {
        const float* Wk = (w == 0) ? Wsrc : (w == 1) ? Wdst : W;
        float acc[4][4];
#pragma unroll
        for (int u = 0; u < 4; ++u)
#pragma unroll
            for (int v = 0; v < 4; ++v) acc[u][v] = 0.f;

#pragma unroll 4
        for (int k = 0; k < 128; ++k) {
            float4 wv = *(const float4*)&Wk[k * 128 + j0];
            float4 xv = *(const float4*)&xsT[k * 32 + m0];
            acc[0][0] = fmaf(xv.x, wv.x, acc[0][0]);
            acc[0][1] = fmaf(xv.x, wv.y, acc[0][1]);
            acc[0][2] = fmaf(xv.x, wv.z, acc[0][2]);
            acc[0][3] = fmaf(xv.x, wv.w, acc[0][3]);
            acc[1][0] = fmaf(xv.y, wv.x, acc[1][0]);
            acc[1][1] = fmaf(xv.y, wv.y, acc[1][1]);
            acc[1][2] = fmaf(xv.y, wv.z, acc[1][2]);
            acc[1][3] = fmaf(xv.y, wv.w, acc[1][3]);
            acc[2][0] = fmaf(xv.z, wv.x, acc[2][0]);
            acc[2][1] = fmaf(xv.z, wv.y, acc[2][1]);
            acc[2][2] = fmaf(xv.z, wv.z, acc[2][2]);
            acc[2][3] = fmaf(xv.z, wv.w, acc[2][3]);
            acc[3][0] = fmaf(xv.w, wv.x, acc[3][0]);
            acc[3][1] = fmaf(xv.w, wv.y, acc[3][1]);
            acc[3][2] = fmaf(xv.w, wv.z, acc[3][2]);
            acc[3][3] = fmaf(xv.w, wv.w, acc[3][3]);
        }

#pragma unroll
        for (int u = 0; u < 4; ++u) {
            int node = n0 + m0 + u;
            if (node >= NN) continue;
            float4 o;
            if (w == 0) {
                o.x = acc[u][0] + p[u][0] + bp[0];
                o.y = acc[u][1] + p[u][1] + bp[1];
                o.z = acc[u][2] + p[u][2] + bp[2];
                o.w = acc[u][3] + p[u][3] + bp[3];
                *(float4*)&As[node * 128 + j0] = o;
            } else if (w == 1) {
                o.x = acc[u][0] + p[u][0];
                o.y = acc[u][1] + p[u][1];
                o.z = acc[u][2] + p[u][2];
                o.w = acc[u][3] + p[u][3];
                *(float4*)&Ad[node * 128 + j0] = o;
            } else {
                o.x = acc[u][0] - p[u][0];
                o.y = acc[u][1] - p[u][1];
                o.z = acc[u][2] - p[u][2];
                o.w = acc[u][3] - p[u][3];
                *(float4*)&Xc[node * 128 + j0] = o;
            }
        }
    }
}

// ---------------- CSR build ----------------
__global__ __launch_bounds__(256) void hist_kernel(const int* __restrict__ ei, int* __restrict__ counts)
{
    int e = blockIdx.x * 256 + threadIdx.x;
    if (e < NE) atomicAdd(&counts[ei[2 * e]], 1);
}

__global__ __launch_bounds__(1024) void scan_kernel(const int* __restrict__ counts,
                                                    int* __restrict__ offsets, int* __restrict__ cursor)
{
    __shared__ int sums[1024];
    const int t = threadIdx.x;
    const int C = (NN + 1023) / 1024;
    int lo = t * C, hi = min(lo + C, NN);
    int s = 0;
    for (int i = lo; i < hi; ++i) s += counts[i];
    sums[t] = s;
    __syncthreads();
    for (int d = 1; d < 1024; d <<= 1) {
        int v = (t >= d) ? sums[t - d] : 0;
        __syncthreads();
        sums[t] += v;
        __syncthreads();
    }
    int run = (t == 0) ? 0 : sums[t - 1];
    for (int i = lo; i < hi; ++i) {
        offsets[i] = run;
        cursor[i] = run;
        run += counts[i];
    }
    if (t == 1023) offsets[NN] = sums[1023];
}

__global__ __launch_bounds__(256) void scatter_kernel(const int* __restrict__ ei,
                                                      int* __restrict__ cursor, int* __restrict__ perm)
{
    int e = blockIdx.x * 256 + threadIdx.x;
    if (e < NE) {
        int r = ei[2 * e];
        int p = atomicAdd(&cursor[r], 1);
        perm[p] = e;
    }
}

// ---------------- Kernel 6: fused edge MLP + online softmax + aggregate ----------------
#define GROUPS 4
#define EB 4

__global__ __launch_bounds__(256) void edge_aggregate(
    const float* __restrict__ pos, const int* __restrict__ ei,
    const float* __restrict__ Wpos, const float* __restrict__ bpos,
    const float* __restrict__ Wa1, const float* __restrict__ ba1,
    const float* __restrict__ Wa2, const float* __restrict__ ba2,
    const float* __restrict__ As, const float* __restrict__ Ad,
    const float* __restrict__ Xc,
    const int* __restrict__ offsets, const int* __restrict__ perm,
    float* __restrict__ out)
{
    __shared__ float w1t[128 * 128];           // Wa1 transposed [j][k], chunk-swizzled
    __shared__ float w2t[128 * 128];           // Wa2 transposed [j][k], chunk-swizzled
    __shared__ float ebuf[GROUPS][EB][128];    // a0, then relu(h) (reused)
    __shared__ float mbuf[GROUPS][128];
    __shared__ float sbuf[GROUPS][128];
    __shared__ float obuf[GROUPS][128];

    const int t = threadIdx.x;
    const int g = t >> 6;     // wave-group 0..3
    const int l = t & 63;     // lane; owns channels l and l+64

    // stage weights transposed with XOR chunk swizzle: element (k,j) -> w[j][ (kc^(j&31))*4 + k&3 ]
    for (int idx = t; idx < 128 * 128; idx += 256) {
        int k = idx >> 7, j = idx & 127;
        int col = (((k >> 2) ^ (j & 31)) << 2) | (k & 3);
        w1t[j * 128 + col] = Wa1[idx];
        w2t[j * 128 + col] = Wa2[idx];
    }
    const float b1_0 = ba1[l], b1_1 = ba1[l + 64];
    const float b2_0 = ba2[l], b2_1 = ba2[l + 64];
    __syncthreads();

    const int sw = l & 31;

    for (int node = blockIdx.x; node < NN; node += gridDim.x) {
        const int start = offsets[node], end = offsets[node + 1];
        const float as0 = As[node * 128 + l];
        const float as1 = As[node * 128 + l + 64];
        float m0v = 0.f, m1v = 0.f, s0 = 0.f, s1 = 0.f, o0 = 0.f, o1 = 0.f;

        for (int base = start + g * EB; base < end; base += GROUPS * EB) {
            int c[EB];
            bool act[EB];
#pragma unroll
            for (int e = 0; e < EB; ++e) {
                act[e] = (base + e) < end;
                c[e] = act[e] ? ei[2 * perm[base + e] + 1] : 0;
            }
            // a0 = As[r] - Ad[c]  -> ebuf (wave-local, no barrier needed)
#pragma unroll
            for (int e = 0; e < EB; ++e) {
                float ad0 = Ad[c[e] * 128 + l];
                float ad1 = Ad[c[e] * 128 + l + 64];
                ebuf[g][e][l] = as0 - ad0;
                ebuf[g][e][l + 64] = as1 - ad1;
            }
            // matvec1: h = a0 @ Wa1 + ba1
            float h0[EB], h1[EB];
#pragma unroll
            for (int e = 0; e < EB; ++e) { h0[e] = b1_0; h1[e] = b1_1; }
#pragma unroll 8
            for (int kc = 0; kc < 32; ++kc) {
                float4 wA = *(const float4*)&w1t[l * 128 + ((kc ^ sw) << 2)];
                float4 wB = *(const float4*)&w1t[(l + 64) * 128 + ((kc ^ sw) << 2)];
#pragma unroll
                for (int e = 0; e < EB; ++e) {
                    float4 a = *(const float4*)&ebuf[g][e][kc << 2];
                    h0[e] = fmaf(a.w, wA.w, fmaf(a.z, wA.z, fmaf(a.y, wA.y, fmaf(a.x, wA.x, h0[e]))));
                    h1[e] = fmaf(a.w, wB.w, fmaf(a.z, wB.z, fmaf(a.y, wB.y, fmaf(a.x, wB.x, h1[e]))));
                }
            }
            // relu -> ebuf (overwrite after all reads)
#pragma unroll
            for (int e = 0; e < EB; ++e) {
                ebuf[g][e][l] = fmaxf(h0[e], 0.f);
                ebuf[g][e][l + 64] = fmaxf(h1[e], 0.f);
            }
            // matvec2: alpha = h @ Wa2 + ba2
            float al0[EB], al1[EB];
#pragma unroll
            for (int e = 0; e < EB; ++e) { al0[e] = b2_0; al1[e] = b2_1; }
#pragma unroll 8
            for (int kc = 0; kc < 32; ++kc) {
                float4 wA = *(const float4*)&w2t[l * 128 + ((kc ^ sw) << 2)];
                float4 wB = *(const float4*)&w2t[(l + 64) * 128 + ((kc ^ sw) << 2)];
#pragma unroll
                for (int e = 0; e < EB; ++e) {
                    float4 a = *(const float4*)&ebuf[g][e][kc << 2];
                    al0[e] = fmaf(a.w, wA.w, fmaf(a.z, wA.z, fmaf(a.y, wA.y, fmaf(a.x, wA.x, al0[e]))));
                    al1[e] = fmaf(a.w, wB.w, fmaf(a.z, wB.z, fmaf(a.y, wB.y, fmaf(a.x, wB.x, al1[e]))));
                }
            }
            // online softmax update per channel (m init 0 == maximum(seg_max,0) clamp)
#pragma unroll
            for (int e = 0; e < EB; ++e) {
                if (act[e]) {
                    float xc0 = Xc[c[e] * 128 + l];
                    float xc1 = Xc[c[e] * 128 + l + 64];
                    float a = al0[e];
                    float mn = fmaxf(m0v, a);
                    float scl = __expf(m0v - mn);
                    float wv = __expf(a - mn);
                    s0 = s0 * scl + wv;
                    o0 = o0 * scl + wv * xc0;
                    m0v = mn;
                    a = al1[e];
                    mn = fmaxf(m1v, a);
                    scl = __expf(m1v - mn);
                    wv = __expf(a - mn);
                    s1 = s1 * scl + wv;
                    o1 = o1 * scl + wv * xc1;
                    m1v = mn;
                }
            }
        }
        // merge the 4 groups
        mbuf[g][l] = m0v; mbuf[g][l + 64] = m1v;
        sbuf[g][l] = s0;  sbuf[g][l + 64] = s1;
        obuf[g][l] = o0;  obuf[g][l + 64] = o1;
        __syncthreads();
        if (t < 128) {
            int j = t;
            float M = fmaxf(fmaxf(mbuf[0][j], mbuf[1][j]), fmaxf(mbuf[2][j], mbuf[3][j]));
            float S = 0.f, O = 0.f;
#pragma unroll
            for (int gg = 0; gg < GROUPS; ++gg) {
                float scl = __expf(mbuf[gg][j] - M);
                S += sbuf[gg][j] * scl;
                O += obuf[gg][j] * scl;
            }
            // Pb[r] = pos[r]@Wpos + bpos; out = (O + Pb*S) / (S + EPS)
            float pb = bpos[j] + pos[node * 3] * Wpos[j] + pos[node * 3 + 1] * Wpos[128 + j]
                     + pos[node * 3 + 2] * Wpos[256 + j];
            out[node * 128 + j] = (O + pb * S) / (S + EPSV);
        }
        __syncthreads();
    }
}

extern "C" void kernel_launch(void* const* d_in, const int* in_sizes, int n_in,
                              void* d_out, int out_size, void* d_ws, size_t ws_size,
                              hipStream_t stream)
{
    const float* x    = (const float*)d_in[0];
    const float* pos  = (const float*)d_in[1];
    const int*   ei   = (const int*)d_in[2];
    const float* W    = (const float*)d_in[3];
    const float* Wsrc = (const float*)d_in[4];
    const float* Wdst = (const float*)d_in[5];
    const float* Wpos = (const float*)d_in[6];
    const float* bpos = (const float*)d_in[7];
    const float* Wa1  = (const float*)d_in[8];
    const float* ba1  = (const float*)d_in[9];
    const float* Wa2  = (const float*)d_in[10];
    const float* ba2  = (const float*)d_in[11];
    float* out = (float*)d_out;

    // workspace layout: 3 x N*128 floats + ints (offsets, cursor, counts, perm) ~= 79.2 MB
    float* As = (float*)d_ws;
    float* Ad = As + (size_t)NN * DD;
    float* Xc = Ad + (size_t)NN * DD;
    int* offsets = (int*)(Xc + (size_t)NN * DD);
    int* cursor  = offsets + (NN + 1);
    int* counts  = cursor + NN;
    int* perm    = counts + NN;

    node_precompute<<<(NN + 31) / 32, 256, 0, stream>>>(x, pos, W, Wsrc, Wdst, Wpos, bpos, As, Ad, Xc);
    hipMemsetAsync(counts, 0, NN * sizeof(int), stream);
    hist_kernel<<<(NE + 255) / 256, 256, 0, stream>>>(ei, counts);
    scan_kernel<<<1, 1024, 0, stream>>>(counts, offsets, cursor);
    scatter_kernel<<<(NE + 255) / 256, 256, 0, stream>>>(ei, cursor, perm);
    edge_aggregate<<<2048, 256, 0, stream>>>(pos, ei, Wpos, bpos, Wa1, ba1, Wa2, ba2,
                                             As, Ad, Xc, offsets, perm, out);
}

// Round 2
// 969.987 us; speedup vs baseline: 2.8827x; 2.8827x over previous
//
#include <hip/hip_runtime.h>
#include <math.h>

#define NN 50000
#define NE 500000
#define DD 128
#define EPSV 1e-12f

typedef short short8 __attribute__((ext_vector_type(8)));
typedef float f32x4 __attribute__((ext_vector_type(4)));

__device__ __forceinline__ ushort f2bf(float f) {
    union { float f; unsigned u; } v; v.f = f;
    unsigned r = (v.u + 0x7FFFu + ((v.u >> 16) & 1u)) >> 16;
    return (ushort)r;
}

// ---------------- Kernel 1: node precompute ----------------
// As = x@Wsrc + P + bpos ; Ad = x@Wdst + P ; Xc = x@W - P ; P = pos@Wpos
__global__ __launch_bounds__(256) void node_precompute(
    const float* __restrict__ x, const float* __restrict__ pos,
    const float* __restrict__ W, const float* __restrict__ Wsrc,
    const float* __restrict__ Wdst, const float* __restrict__ Wpos,
    const float* __restrict__ bpos,
    float* __restrict__ As, float* __restrict__ Ad, float* __restrict__ Xc)
{
    __shared__ float xsT[128 * 32]; // [k][m], transposed x tile
    const int t = threadIdx.x;
    const int n0 = blockIdx.x * 32;
    const int jg = t & 31, mg = t >> 5;
    const int j0 = jg * 4, m0 = mg * 4;

    for (int idx = t; idx < 32 * 128; idx += 256) {
        int i = idx >> 7, k = idx & 127;
        int node = n0 + i;
        xsT[k * 32 + i] = (node < NN) ? x[node * 128 + k] : 0.0f;
    }
    __syncthreads();

    float wp[3][4];
#pragma unroll
    for (int d = 0; d < 3; ++d) {
        float4 w4 = *(const float4*)&Wpos[d * 128 + j0];
        wp[d][0] = w4.x; wp[d][1] = w4.y; wp[d][2] = w4.z; wp[d][3] = w4.w;
    }
    float4 bp4 = *(const float4*)&bpos[j0];
    float bp[4] = {bp4.x, bp4.y, bp4.z, bp4.w};
    float p[4][4];
#pragma unroll
    for (int u = 0; u < 4; ++u) {
        int node = n0 + m0 + u;
        float pd0 = 0.f, pd1 = 0.f, pd2 = 0.f;
        if (node < NN) { pd0 = pos[node * 3]; pd1 = pos[node * 3 + 1]; pd2 = pos[node * 3 + 2]; }
#pragma unroll
        for (int v = 0; v < 4; ++v)
            p[u][v] = pd0 * wp[0][v] + pd1 * wp[1][v] + pd2 * wp[2][v];
    }

#pragma unroll 1
    for (int w = 0; w < 3; ++w) {
        const float* Wk = (w == 0) ? Wsrc : (w == 1) ? Wdst : W;
        float acc[4][4];
#pragma unroll
        for (int u = 0; u < 4; ++u)
#pragma unroll
            for (int v = 0; v < 4; ++v) acc[u][v] = 0.f;

#pragma unroll 4
        for (int k = 0; k < 128; ++k) {
            float4 wv = *(const float4*)&Wk[k * 128 + j0];
            float4 xv = *(const float4*)&xsT[k * 32 + m0];
            acc[0][0] = fmaf(xv.x, wv.x, acc[0][0]);
            acc[0][1] = fmaf(xv.x, wv.y, acc[0][1]);
            acc[0][2] = fmaf(xv.x, wv.z, acc[0][2]);
            acc[0][3] = fmaf(xv.x, wv.w, acc[0][3]);
            acc[1][0] = fmaf(xv.y, wv.x, acc[1][0]);
            acc[1][1] = fmaf(xv.y, wv.y, acc[1][1]);
            acc[1][2] = fmaf(xv.y, wv.z, acc[1][2]);
            acc[1][3] = fmaf(xv.y, wv.w, acc[1][3]);
            acc[2][0] = fmaf(xv.z, wv.x, acc[2][0]);
            acc[2][1] = fmaf(xv.z, wv.y, acc[2][1]);
            acc[2][2] = fmaf(xv.z, wv.z, acc[2][2]);
            acc[2][3] = fmaf(xv.z, wv.w, acc[2][3]);
            acc[3][0] = fmaf(xv.w, wv.x, acc[3][0]);
            acc[3][1] = fmaf(xv.w, wv.y, acc[3][1]);
            acc[3][2] = fmaf(xv.w, wv.z, acc[3][2]);
            acc[3][3] = fmaf(xv.w, wv.w, acc[3][3]);
        }

#pragma unroll
        for (int u = 0; u < 4; ++u) {
            int node = n0 + m0 + u;
            if (node >= NN) continue;
            float4 o;
            if (w == 0) {
                o.x = acc[u][0] + p[u][0] + bp[0];
                o.y = acc[u][1] + p[u][1] + bp[1];
                o.z = acc[u][2] + p[u][2] + bp[2];
                o.w = acc[u][3] + p[u][3] + bp[3];
                *(float4*)&As[node * 128 + j0] = o;
            } else if (w == 1) {
                o.x = acc[u][0] + p[u][0];
                o.y = acc[u][1] + p[u][1];
                o.z = acc[u][2] + p[u][2];
                o.w = acc[u][3] + p[u][3];
                *(float4*)&Ad[node * 128 + j0] = o;
            } else {
                o.x = acc[u][0] - p[u][0];
                o.y = acc[u][1] - p[u][1];
                o.z = acc[u][2] - p[u][2];
                o.w = acc[u][3] - p[u][3];
                *(float4*)&Xc[node * 128 + j0] = o;
            }
        }
    }
}

// ---------------- CSR build ----------------
__global__ __launch_bounds__(256) void hist_kernel(const int* __restrict__ ei, int* __restrict__ counts)
{
    int e = blockIdx.x * 256 + threadIdx.x;
    if (e < NE) atomicAdd(&counts[ei[2 * e]], 1);
}

__global__ __launch_bounds__(1024) void scan_kernel(const int* __restrict__ counts,
                                                    int* __restrict__ offsets, int* __restrict__ cursor)
{
    __shared__ int sums[1024];
    const int t = threadIdx.x;
    const int C = (NN + 1023) / 1024;
    int lo = t * C, hi = min(lo + C, NN);
    int s = 0;
    for (int i = lo; i < hi; ++i) s += counts[i];
    sums[t] = s;
    __syncthreads();
    for (int d = 1; d < 1024; d <<= 1) {
        int v = (t >= d) ? sums[t - d] : 0;
        __syncthreads();
        sums[t] += v;
        __syncthreads();
    }
    int run = (t == 0) ? 0 : sums[t - 1];
    for (int i = lo; i < hi; ++i) {
        offsets[i] = run;
        cursor[i] = run;
        run += counts[i];
    }
    if (t == 1023) offsets[NN] = sums[1023];
}

// stores the edge's col index directly into CSR slot (perm never needed downstream)
__global__ __launch_bounds__(256) void scatter_kernel(const int* __restrict__ ei,
                                                      int* __restrict__ cursor, int* __restrict__ colc)
{
    int e = blockIdx.x * 256 + threadIdx.x;
    if (e < NE) {
        int r = ei[2 * e];
        int c = ei[2 * e + 1];
        int p = atomicAdd(&cursor[r], 1);
        colc[p] = c;
    }
}

// ---------------- Fused edge MLP (MFMA) + online softmax + aggregate ----------------
// One wave owns one node. Per 16-edge tile:
//   A-frag (16 edges x K=32 chunk): a0 = As[r]-Ad[c], gathered direct from global -> bf16
//   mv1: acc[nb] += mfma(af[kc], W1frag[nb][kc])  (32 MFMA)
//   relu -> bf16 -> per-wave LDS hbuf (XOR-swizzled) -> A-frags for mv2 (32 MFMA)
//   online softmax per (channel, lane-group) in registers; shfl merge at node end.
// LDS: W1+W2 bf16 swizzled 64KB + 4x4KB hbuf = 80KB -> 2 blocks/CU.
__global__ __launch_bounds__(256) void edge_aggregate(
    const float* __restrict__ pos,
    const float* __restrict__ Wpos, const float* __restrict__ bpos,
    const float* __restrict__ Wa1, const float* __restrict__ ba1,
    const float* __restrict__ Wa2, const float* __restrict__ ba2,
    const float* __restrict__ As, const float* __restrict__ Ad,
    const float* __restrict__ Xc,
    const int* __restrict__ offsets, const int* __restrict__ colc,
    float* __restrict__ out)
{
    __shared__ ushort wl[2][16384];   // [mat][ j*128 + ((k>>3)^(j&15))*8 + (k&7) ]
    __shared__ ushort hb[4][2048];    // per-wave h tile [e][ch], same swizzle

    const int t = threadIdx.x;
    const int w = t >> 6;
    const int l = t & 63;
    const int g = l >> 4;       // k-group / edge-group
    const int low = l & 15;     // A row (edge) for frags; D col (channel low bits)

    // stage W1/W2 as bf16 with XOR slot swizzle (one-time)
    for (int idx = t; idx < 16384; idx += 256) {
        int k = idx >> 7, j = idx & 127;
        int addr = j * 128 + (((k >> 3) ^ (j & 15)) << 3) + (k & 7);
        wl[0][addr] = f2bf(Wa1[idx]);
        wl[1][addr] = f2bf(Wa2[idx]);
    }
    float b1v[8], b2v[8];
#pragma unroll
    for (int nb = 0; nb < 8; ++nb) {
        b1v[nb] = ba1[nb * 16 + low];
        b2v[nb] = ba2[nb * 16 + low];
    }
    __syncthreads();

    for (int node = blockIdx.x * 4 + w; node < NN; node += gridDim.x * 4) {
        const int start = offsets[node], end = offsets[node + 1];
        const int deg = end - start;

        // online-softmax state per channel ch = nb*16+low, over this lane-group's edges.
        // m init 0 implements the maximum(seg_max, 0) clamp exactly.
        float m[8], s[8], o[8];
#pragma unroll
        for (int nb = 0; nb < 8; ++nb) { m[nb] = 0.f; s[nb] = 0.f; o[nb] = 0.f; }

        if (deg > 0) {
            const int cend = end - 1;
            // preload this lane's As-row slices (reused across tiles)
            float4 asr[8];
            const float* asp = As + (size_t)node * 128;
#pragma unroll
            for (int kc = 0; kc < 4; ++kc) {
                asr[kc * 2]     = *(const float4*)&asp[kc * 32 + g * 8];
                asr[kc * 2 + 1] = *(const float4*)&asp[kc * 32 + g * 8 + 4];
            }

            for (int base = start; base < end; base += 16) {
                // ----- A fragments: a0[edge=low][k] -----
                int ca = colc[min(base + low, cend)];
                short8 af[4];
#pragma unroll
                for (int kc = 0; kc < 4; ++kc) {
                    const float* adp = Ad + (size_t)ca * 128 + kc * 32 + g * 8;
                    float4 d0 = *(const float4*)adp;
                    float4 d1 = *(const float4*)(adp + 4);
                    float4 a0 = asr[kc * 2], a1 = asr[kc * 2 + 1];
                    short8 v;
                    v[0] = (short)f2bf(a0.x - d0.x);
                    v[1] = (short)f2bf(a0.y - d0.y);
                    v[2] = (short)f2bf(a0.z - d0.z);
                    v[3] = (short)f2bf(a0.w - d0.w);
                    v[4] = (short)f2bf(a1.x - d1.x);
                    v[5] = (short)f2bf(a1.y - d1.y);
                    v[6] = (short)f2bf(a1.z - d1.z);
                    v[7] = (short)f2bf(a1.w - d1.w);
                    af[kc] = v;
                }

                // ----- mv1: h = a0 @ W1 -----
                f32x4 acc[8];
#pragma unroll
                for (int nb = 0; nb < 8; ++nb) { acc[nb][0]=0.f; acc[nb][1]=0.f; acc[nb][2]=0.f; acc[nb][3]=0.f; }
#pragma unroll
                for (int nb = 0; nb < 8; ++nb) {
                    int j = nb * 16 + low;
#pragma unroll
                    for (int kc = 0; kc < 4; ++kc) {
                        short8 bf = *(const short8*)&wl[0][j * 128 + (((kc * 4 + g) ^ low) << 3)];
                        acc[nb] = __builtin_amdgcn_mfma_f32_16x16x32_bf16(af[kc], bf, acc[nb], 0, 0, 0);
                    }
                }

                // ----- bias + relu -> hbuf (swizzled bf16) -----
#pragma unroll
                for (int nb = 0; nb < 8; ++nb) {
                    int chs = nb * 2 + (low >> 3);   // ch>>3
#pragma unroll
                    for (int r = 0; r < 4; ++r) {
                        int e = g * 4 + r;           // D row = edge
                        float hv = fmaxf(acc[nb][r] + b1v[nb], 0.f);
                        hb[w][e * 128 + ((chs ^ e) << 3) + (low & 7)] = f2bf(hv);
                    }
                }

                // ----- mv2: alpha = relu(h) @ W2 -----
                short8 hf[4];
#pragma unroll
                for (int kc = 0; kc < 4; ++kc)
                    hf[kc] = *(const short8*)&hb[w][low * 128 + (((kc * 4 + g) ^ low) << 3)];
                f32x4 acc2[8];
#pragma unroll
                for (int nb = 0; nb < 8; ++nb) { acc2[nb][0]=0.f; acc2[nb][1]=0.f; acc2[nb][2]=0.f; acc2[nb][3]=0.f; }
#pragma unroll
                for (int nb = 0; nb < 8; ++nb) {
                    int j = nb * 16 + low;
#pragma unroll
                    for (int kc = 0; kc < 4; ++kc) {
                        short8 bf = *(const short8*)&wl[1][j * 128 + (((kc * 4 + g) ^ low) << 3)];
                        acc2[nb] = __builtin_amdgcn_mfma_f32_16x16x32_bf16(hf[kc], bf, acc2[nb], 0, 0, 0);
                    }
                }

                // ----- online softmax update (lane's edges: e = g*4+r) -----
#pragma unroll
                for (int r = 0; r < 4; ++r) {
                    int slot = base + g * 4 + r;
                    bool valid = slot < end;
                    int cr = colc[min(slot, cend)];
                    const float* xcp = Xc + (size_t)cr * 128 + low;
#pragma unroll
                    for (int nb = 0; nb < 8; ++nb) {
                        float a = acc2[nb][r] + b2v[nb];
                        float xc = xcp[nb * 16];
                        float mn = valid ? fmaxf(m[nb], a) : m[nb];
                        float scl = __expf(m[nb] - mn);
                        float wv = valid ? __expf(a - mn) : 0.f;
                        s[nb] = s[nb] * scl + wv;
                        o[nb] = o[nb] * scl + wv * xc;
                        m[nb] = mn;
                    }
                }
            }
        }

        // merge the 4 lane-groups (channels live on lanes with same low)
#pragma unroll
        for (int off = 16; off <= 32; off <<= 1) {
#pragma unroll
            for (int nb = 0; nb < 8; ++nb) {
                float m2 = __shfl_xor(m[nb], off);
                float s2 = __shfl_xor(s[nb], off);
                float o2 = __shfl_xor(o[nb], off);
                float M = fmaxf(m[nb], m2);
                float e1 = __expf(m[nb] - M), e2 = __expf(m2 - M);
                s[nb] = s[nb] * e1 + s2 * e2;
                o[nb] = o[nb] * e1 + o2 * e2;
                m[nb] = M;
            }
        }

        if (l < 16) {
            float p0 = pos[node * 3], p1 = pos[node * 3 + 1], p2 = pos[node * 3 + 2];
#pragma unroll
            for (int nb = 0; nb < 8; ++nb) {
                int ch = nb * 16 + l;
                float pb = bpos[ch] + p0 * Wpos[ch] + p1 * Wpos[128 + ch] + p2 * Wpos[256 + ch];
                out[(size_t)node * 128 + ch] = (o[nb] + pb * s[nb]) / (s[nb] + EPSV);
            }
        }
    }
}

extern "C" void kernel_launch(void* const* d_in, const int* in_sizes, int n_in,
                              void* d_out, int out_size, void* d_ws, size_t ws_size,
                              hipStream_t stream)
{
    const float* x    = (const float*)d_in[0];
    const float* pos  = (const float*)d_in[1];
    const int*   ei   = (const int*)d_in[2];
    const float* W    = (const float*)d_in[3];
    const float* Wsrc = (const float*)d_in[4];
    const float* Wdst = (const float*)d_in[5];
    const float* Wpos = (const float*)d_in[6];
    const float* bpos = (const float*)d_in[7];
    const float* Wa1  = (const float*)d_in[8];
    const float* ba1  = (const float*)d_in[9];
    const float* Wa2  = (const float*)d_in[10];
    const float* ba2  = (const float*)d_in[11];
    float* out = (float*)d_out;

    // workspace: 3 x N*128 floats + offsets/cursor/counts/colc
    float* As = (float*)d_ws;
    float* Ad = As + (size_t)NN * DD;
    float* Xc = Ad + (size_t)NN * DD;
    int* offsets = (int*)(Xc + (size_t)NN * DD);
    int* cursor  = offsets + (NN + 1);
    int* counts  = cursor + NN;
    int* colc    = counts + NN;

    node_precompute<<<(NN + 31) / 32, 256, 0, stream>>>(x, pos, W, Wsrc, Wdst, Wpos, bpos, As, Ad, Xc);
    hipMemsetAsync(counts, 0, NN * sizeof(int), stream);
    hist_kernel<<<(NE + 255) / 256, 256, 0, stream>>>(ei, counts);
    scan_kernel<<<1, 1024, 0, stream>>>(counts, offsets, cursor);
    scatter_kernel<<<(NE + 255) / 256, 256, 0, stream>>>(ei, cursor, colc);
    edge_aggregate<<<2048, 256, 0, stream>>>(pos, Wpos, bpos, Wa1, ba1, Wa2, ba2,
                                             As, Ad, Xc, offsets, colc, out);
}

// Round 3
// 386.967 us; speedup vs baseline: 7.2259x; 2.5066x over previous
//
#include <hip/hip_runtime.h>
#include <math.h>

#define NN 50000
#define NE 500000
#define NTILES 31250   // NE/16 exact
#define DD 128
#define EPSV 1e-12f

typedef short short8 __attribute__((ext_vector_type(8)));
typedef float f32x4 __attribute__((ext_vector_type(4)));

__device__ __forceinline__ ushort f2bf(float f) {
    union { float f; unsigned u; } v; v.f = f;
    unsigned r = (v.u + 0x7FFFu + ((v.u >> 16) & 1u)) >> 16;
    return (ushort)r;
}
__device__ __forceinline__ float bf2f(unsigned u) {
    union { unsigned u; float f; } v; v.u = u << 16;
    return v.f;
}

// ---------------- Kernel 1: node precompute (MFMA, y selects matrix) ----------------
// y=0: As = x@Wsrc + P + bpos ; y=1: Ad = x@Wdst + P ; y=2: Xc = x@W - P
__global__ __launch_bounds__(256) void node_precompute(
    const float* __restrict__ x, const float* __restrict__ pos,
    const float* __restrict__ W, const float* __restrict__ Wsrc,
    const float* __restrict__ Wdst, const float* __restrict__ Wpos,
    const float* __restrict__ bpos,
    float* __restrict__ As, float* __restrict__ Ad, float* __restrict__ Xc)
{
    __shared__ ushort wsm[16384];
    const int t = threadIdx.x;
    const int w = t >> 6;
    const int l = t & 63;
    const int g = l >> 4;
    const int low = l & 15;
    const int y = blockIdx.y;
    const float* Wsel = (y == 0) ? Wsrc : (y == 1) ? Wdst : W;
    float* dst = (y == 0) ? As : (y == 1) ? Ad : Xc;

    // packed staging: thread handles (k8, j): short8 of 8 consecutive k for column j
    for (int gi = t; gi < 2048; gi += 256) {
        int j = gi & 127, k8 = gi >> 7;
        short8 v;
#pragma unroll
        for (int i = 0; i < 8; ++i)
            v[i] = (short)f2bf(Wsel[(k8 * 8 + i) * 128 + j]);
        *(short8*)&wsm[j * 128 + ((k8 ^ (j & 15)) << 3)] = v;
    }
    // per-channel Wpos/bpos (ch = nb*16+low)
    float wp0[8], wp1[8], wp2[8], bpv[8];
#pragma unroll
    for (int nb = 0; nb < 8; ++nb) {
        int ch = nb * 16 + low;
        wp0[nb] = Wpos[ch]; wp1[nb] = Wpos[128 + ch]; wp2[nb] = Wpos[256 + ch];
        bpv[nb] = bpos[ch];
    }
    __syncthreads();

    const int n0 = (blockIdx.x * 4 + w) * 16;
    const int rowi = min(n0 + low, NN - 1);

    short8 af[4];
#pragma unroll
    for (int kc = 0; kc < 4; ++kc) {
        const float* xp = x + (size_t)rowi * 128 + kc * 32 + g * 8;
        float4 a0 = *(const float4*)xp;
        float4 a1 = *(const float4*)(xp + 4);
        short8 v;
        v[0] = (short)f2bf(a0.x); v[1] = (short)f2bf(a0.y);
        v[2] = (short)f2bf(a0.z); v[3] = (short)f2bf(a0.w);
        v[4] = (short)f2bf(a1.x); v[5] = (short)f2bf(a1.y);
        v[6] = (short)f2bf(a1.z); v[7] = (short)f2bf(a1.w);
        af[kc] = v;
    }

    f32x4 acc[8];
#pragma unroll
    for (int nb = 0; nb < 8; ++nb) { acc[nb][0]=0.f; acc[nb][1]=0.f; acc[nb][2]=0.f; acc[nb][3]=0.f; }
#pragma unroll
    for (int nb = 0; nb < 8; ++nb) {
        int j = nb * 16 + low;
#pragma unroll
        for (int kc = 0; kc < 4; ++kc) {
            short8 bf = *(const short8*)&wsm[j * 128 + (((kc * 4 + g) ^ low) << 3)];
            acc[nb] = __builtin_amdgcn_mfma_f32_16x16x32_bf16(af[kc], bf, acc[nb], 0, 0, 0);
        }
    }

#pragma unroll
    for (int r = 0; r < 4; ++r) {
        int node = n0 + g * 4 + r;
        if (node >= NN) continue;
        float p0 = pos[node * 3], p1 = pos[node * 3 + 1], p2 = pos[node * 3 + 2];
#pragma unroll
        for (int nb = 0; nb < 8; ++nb) {
            float pterm = p0 * wp0[nb] + p1 * wp1[nb] + p2 * wp2[nb];
            float add = (y == 0) ? (pterm + bpv[nb]) : (y == 1) ? pterm : -pterm;
            dst[(size_t)node * 128 + nb * 16 + low] = acc[nb][r] + add;
        }
    }
}

// ---------------- CSR build ----------------
__global__ __launch_bounds__(256) void hist_kernel(const int* __restrict__ ei, int* __restrict__ counts)
{
    int e = blockIdx.x * 256 + threadIdx.x;
    if (e < NE) atomicAdd(&counts[ei[2 * e]], 1);
}

__global__ __launch_bounds__(1024) void scan_kernel(const int* __restrict__ counts,
                                                    int* __restrict__ offsets, int* __restrict__ cursor)
{
    __shared__ int sums[1024];
    const int t = threadIdx.x;
    const int C = (NN + 1023) / 1024;
    int lo = t * C, hi = min(lo + C, NN);
    int s = 0;
    for (int i = lo; i < hi; ++i) s += counts[i];
    sums[t] = s;
    __syncthreads();
    for (int d = 1; d < 1024; d <<= 1) {
        int v = (t >= d) ? sums[t - d] : 0;
        __syncthreads();
        sums[t] += v;
        __syncthreads();
    }
    int run = (t == 0) ? 0 : sums[t - 1];
    for (int i = lo; i < hi; ++i) {
        offsets[i] = run;
        cursor[i] = run;
        run += counts[i];
    }
    if (t == 1023) offsets[NN] = sums[1023];
}

__global__ __launch_bounds__(256) void scatter_kernel(const int* __restrict__ ei,
                                                      int* __restrict__ cursor,
                                                      int* __restrict__ rowc, int* __restrict__ colc)
{
    int e = blockIdx.x * 256 + threadIdx.x;
    if (e < NE) {
        int r = ei[2 * e];
        int c = ei[2 * e + 1];
        int p = atomicAdd(&cursor[r], 1);
        rowc[p] = r;
        colc[p] = c;
    }
}

// ---------------- Pass A: alpha = (relu((As[r]-Ad[c])@W1+b1))@W2+b2, dense 16-edge tiles ----------------
__global__ __launch_bounds__(256) void alpha_kernel(
    const float* __restrict__ As, const float* __restrict__ Ad,
    const float* __restrict__ Wa1, const float* __restrict__ ba1,
    const float* __restrict__ Wa2, const float* __restrict__ ba2,
    const int* __restrict__ rowc, const int* __restrict__ colc,
    ushort* __restrict__ alphaW)
{
    __shared__ ushort wl[2][16384];
    __shared__ ushort hb[4][2048];

    const int t = threadIdx.x;
    const int w = t >> 6;
    const int l = t & 63;
    const int g = l >> 4;
    const int low = l & 15;

    // packed weight staging (ds_write_b128)
    for (int gi = t; gi < 2048; gi += 256) {
        int j = gi & 127, k8 = gi >> 7;
        short8 v1, v2;
#pragma unroll
        for (int i = 0; i < 8; ++i) {
            v1[i] = (short)f2bf(Wa1[(k8 * 8 + i) * 128 + j]);
            v2[i] = (short)f2bf(Wa2[(k8 * 8 + i) * 128 + j]);
        }
        int addr = j * 128 + ((k8 ^ (j & 15)) << 3);
        *(short8*)&wl[0][addr] = v1;
        *(short8*)&wl[1][addr] = v2;
    }
    float b1v[8], b2v[8];
#pragma unroll
    for (int nb = 0; nb < 8; ++nb) {
        b1v[nb] = ba1[nb * 16 + low];
        b2v[nb] = ba2[nb * 16 + low];
    }
    __syncthreads();

    const int nw = gridDim.x * 4;
    const int w0 = blockIdx.x * 4 + w;

    for (int t0 = w0; t0 < NTILES; t0 += 2 * nw) {
        const int t1 = t0 + nw;
        const bool has1 = t1 < NTILES;

        // gather a0 fragments for both tiles
        short8 afA[4], afB[4];
        {
            int slot = t0 * 16 + low;
            int r = rowc[slot], c = colc[slot];
            const float* asp = As + (size_t)r * 128 + g * 8;
            const float* adp = Ad + (size_t)c * 128 + g * 8;
#pragma unroll
            for (int kc = 0; kc < 4; ++kc) {
                float4 s0 = *(const float4*)(asp + kc * 32);
                float4 s1 = *(const float4*)(asp + kc * 32 + 4);
                float4 d0 = *(const float4*)(adp + kc * 32);
                float4 d1 = *(const float4*)(adp + kc * 32 + 4);
                short8 v;
                v[0] = (short)f2bf(s0.x - d0.x); v[1] = (short)f2bf(s0.y - d0.y);
                v[2] = (short)f2bf(s0.z - d0.z); v[3] = (short)f2bf(s0.w - d0.w);
                v[4] = (short)f2bf(s1.x - d1.x); v[5] = (short)f2bf(s1.y - d1.y);
                v[6] = (short)f2bf(s1.z - d1.z); v[7] = (short)f2bf(s1.w - d1.w);
                afA[kc] = v;
            }
        }
        if (has1) {
            int slot = t1 * 16 + low;
            int r = rowc[slot], c = colc[slot];
            const float* asp = As + (size_t)r * 128 + g * 8;
            const float* adp = Ad + (size_t)c * 128 + g * 8;
#pragma unroll
            for (int kc = 0; kc < 4; ++kc) {
                float4 s0 = *(const float4*)(asp + kc * 32);
                float4 s1 = *(const float4*)(asp + kc * 32 + 4);
                float4 d0 = *(const float4*)(adp + kc * 32);
                float4 d1 = *(const float4*)(adp + kc * 32 + 4);
                short8 v;
                v[0] = (short)f2bf(s0.x - d0.x); v[1] = (short)f2bf(s0.y - d0.y);
                v[2] = (short)f2bf(s0.z - d0.z); v[3] = (short)f2bf(s0.w - d0.w);
                v[4] = (short)f2bf(s1.x - d1.x); v[5] = (short)f2bf(s1.y - d1.y);
                v[6] = (short)f2bf(s1.z - d1.z); v[7] = (short)f2bf(s1.w - d1.w);
                afB[kc] = v;
            }
        }

        // mv1 (shared B-fragment reads)
        f32x4 accA[8], accB[8];
#pragma unroll
        for (int nb = 0; nb < 8; ++nb) {
            accA[nb][0]=0.f; accA[nb][1]=0.f; accA[nb][2]=0.f; accA[nb][3]=0.f;
            accB[nb][0]=0.f; accB[nb][1]=0.f; accB[nb][2]=0.f; accB[nb][3]=0.f;
        }
#pragma unroll
        for (int nb = 0; nb < 8; ++nb) {
            int j = nb * 16 + low;
#pragma unroll
            for (int kc = 0; kc < 4; ++kc) {
                short8 bf = *(const short8*)&wl[0][j * 128 + (((kc * 4 + g) ^ low) << 3)];
                accA[nb] = __builtin_amdgcn_mfma_f32_16x16x32_bf16(afA[kc], bf, accA[nb], 0, 0, 0);
                if (has1)
                    accB[nb] = __builtin_amdgcn_mfma_f32_16x16x32_bf16(afB[kc], bf, accB[nb], 0, 0, 0);
            }
        }

        // relu -> hb -> hf (tile A, then tile B; wave-local, lgkmcnt-ordered)
        short8 hfA[4], hfB[4];
#pragma unroll
        for (int nb = 0; nb < 8; ++nb) {
            int chs = nb * 2 + (low >> 3);
#pragma unroll
            for (int r = 0; r < 4; ++r) {
                int e = g * 4 + r;
                hb[w][e * 128 + ((chs ^ e) << 3) + (low & 7)] = f2bf(fmaxf(accA[nb][r] + b1v[nb], 0.f));
            }
        }
#pragma unroll
        for (int kc = 0; kc < 4; ++kc)
            hfA[kc] = *(const short8*)&hb[w][low * 128 + (((kc * 4 + g) ^ low) << 3)];
        if (has1) {
#pragma unroll
            for (int nb = 0; nb < 8; ++nb) {
                int chs = nb * 2 + (low >> 3);
#pragma unroll
                for (int r = 0; r < 4; ++r) {
                    int e = g * 4 + r;
                    hb[w][e * 128 + ((chs ^ e) << 3) + (low & 7)] = f2bf(fmaxf(accB[nb][r] + b1v[nb], 0.f));
                }
            }
#pragma unroll
            for (int kc = 0; kc < 4; ++kc)
                hfB[kc] = *(const short8*)&hb[w][low * 128 + (((kc * 4 + g) ^ low) << 3)];
        }

        // mv2 (shared B-fragment reads)
#pragma unroll
        for (int nb = 0; nb < 8; ++nb) {
            accA[nb][0]=0.f; accA[nb][1]=0.f; accA[nb][2]=0.f; accA[nb][3]=0.f;
            accB[nb][0]=0.f; accB[nb][1]=0.f; accB[nb][2]=0.f; accB[nb][3]=0.f;
        }
#pragma unroll
        for (int nb = 0; nb < 8; ++nb) {
            int j = nb * 16 + low;
#pragma unroll
            for (int kc = 0; kc < 4; ++kc) {
                short8 bf = *(const short8*)&wl[1][j * 128 + (((kc * 4 + g) ^ low) << 3)];
                accA[nb] = __builtin_amdgcn_mfma_f32_16x16x32_bf16(hfA[kc], bf, accA[nb], 0, 0, 0);
                if (has1)
                    accB[nb] = __builtin_amdgcn_mfma_f32_16x16x32_bf16(hfB[kc], bf, accB[nb], 0, 0, 0);
            }
        }

        // store alpha (bf16)
#pragma unroll
        for (int nb = 0; nb < 8; ++nb) {
#pragma unroll
            for (int r = 0; r < 4; ++r) {
                alphaW[(size_t)(t0 * 16 + g * 4 + r) * 128 + nb * 16 + low] = f2bf(accA[nb][r] + b2v[nb]);
                if (has1)
                    alphaW[(size_t)(t1 * 16 + g * 4 + r) * 128 + nb * 16 + low] = f2bf(accB[nb][r] + b2v[nb]);
            }
        }
    }
}

// ---------------- Pass B: per-node softmax + aggregate ----------------
__global__ __launch_bounds__(256) void aggregate_kernel(
    const float* __restrict__ pos,
    const float* __restrict__ Wpos, const float* __restrict__ bpos,
    const float* __restrict__ Xc,
    const int* __restrict__ offsets, const int* __restrict__ colc,
    const ushort* __restrict__ alphaW, float* __restrict__ out)
{
    const int l = threadIdx.x & 63;
    const int wid = blockIdx.x * 4 + (threadIdx.x >> 6);
    const int nw = gridDim.x * 4;
    const int ch0 = 2 * l, ch1 = 2 * l + 1;

    // per-lane channel constants
    const float wpa0 = Wpos[ch0], wpa1 = Wpos[128 + ch0], wpa2 = Wpos[256 + ch0];
    const float wpb0 = Wpos[ch1], wpb1 = Wpos[128 + ch1], wpb2 = Wpos[256 + ch1];
    const float bpa = bpos[ch0], bpb = bpos[ch1];

    for (int node = wid; node < NN; node += nw) {
        const int aoff = offsets[node];
        const int deg = offsets[node + 1] - aoff;
        const ushort* ap = alphaW + (size_t)aoff * 128 + ch0;

        float m0 = 0.f, m1 = 0.f;
#pragma unroll 4
        for (int e = 0; e < deg; ++e) {
            unsigned v = *(const unsigned*)(ap + (size_t)e * 128);
            m0 = fmaxf(m0, bf2f(v & 0xffffu));
            m1 = fmaxf(m1, bf2f(v >> 16));
        }
        float s0 = 0.f, s1 = 0.f, o0 = 0.f, o1 = 0.f;
#pragma unroll 2
        for (int e = 0; e < deg; ++e) {
            unsigned v = *(const unsigned*)(ap + (size_t)e * 128);
            int c = colc[aoff + e];
            float2 xc = *(const float2*)&Xc[(size_t)c * 128 + ch0];
            float w0 = __expf(bf2f(v & 0xffffu) - m0);
            float w1 = __expf(bf2f(v >> 16) - m1);
            s0 += w0; s1 += w1;
            o0 = fmaf(w0, xc.x, o0); o1 = fmaf(w1, xc.y, o1);
        }
        float p0 = pos[node * 3], p1 = pos[node * 3 + 1], p2 = pos[node * 3 + 2];
        float pb0 = bpa + p0 * wpa0 + p1 * wpa1 + p2 * wpa2;
        float pb1 = bpb + p0 * wpb0 + p1 * wpb1 + p2 * wpb2;
        float2 r;
        r.x = (o0 + pb0 * s0) / (s0 + EPSV);
        r.y = (o1 + pb1 * s1) / (s1 + EPSV);
        *(float2*)&out[(size_t)node * 128 + ch0] = r;
    }
}

extern "C" void kernel_launch(void* const* d_in, const int* in_sizes, int n_in,
                              void* d_out, int out_size, void* d_ws, size_t ws_size,
                              hipStream_t stream)
{
    const float* x    = (const float*)d_in[0];
    const float* pos  = (const float*)d_in[1];
    const int*   ei   = (const int*)d_in[2];
    const float* W    = (const float*)d_in[3];
    const float* Wsrc = (const float*)d_in[4];
    const float* Wdst = (const float*)d_in[5];
    const float* Wpos = (const float*)d_in[6];
    const float* bpos = (const float*)d_in[7];
    const float* Wa1  = (const float*)d_in[8];
    const float* ba1  = (const float*)d_in[9];
    const float* Wa2  = (const float*)d_in[10];
    const float* ba2  = (const float*)d_in[11];
    float* out = (float*)d_out;

    // ws layout: As/Ad/Xc (76.8MB) + ints (4.6MB) + alpha bf16 (128MB) ~= 209.4MB
    float* As = (float*)d_ws;
    float* Ad = As + (size_t)NN * DD;
    float* Xc = Ad + (size_t)NN * DD;
    int* offsets = (int*)(Xc + (size_t)NN * DD);
    int* cursor  = offsets + (NN + 1);
    int* counts  = cursor + NN;
    int* rowc    = counts + NN;
    int* colc    = rowc + NE;
    ushort* alphaW = (ushort*)(colc + NE);

    node_precompute<<<dim3((NN + 63) / 64, 3), 256, 0, stream>>>(
        x, pos, W, Wsrc, Wdst, Wpos, bpos, As, Ad, Xc);
    hipMemsetAsync(counts, 0, NN * sizeof(int), stream);
    hist_kernel<<<(NE + 255) / 256, 256, 0, stream>>>(ei, counts);
    scan_kernel<<<1, 1024, 0, stream>>>(counts, offsets, cursor);
    scatter_kernel<<<(NE + 255) / 256, 256, 0, stream>>>(ei, cursor, rowc, colc);
    alpha_kernel<<<512, 256, 0, stream>>>(As, Ad, Wa1, ba1, Wa2, ba2, rowc, colc, alphaW);
    aggregate_kernel<<<4096, 256, 0, stream>>>(pos, Wpos, bpos, Xc, offsets, colc, alphaW, out);
}

// Round 4
// 382.442 us; speedup vs baseline: 7.3114x; 1.0118x over previous
//
#include <hip/hip_runtime.h>
#include <math.h>

#define NN 50000
#define NE 500000
#define NTILES 31250   // NE/16 exact
#define DD 128
#define EPSV 1e-12f

typedef short short8 __attribute__((ext_vector_type(8)));
typedef float f32x4 __attribute__((ext_vector_type(4)));

__device__ __forceinline__ ushort f2bf(float f) {
    union { float f; unsigned u; } v; v.f = f;
    unsigned r = (v.u + 0x7FFFu + ((v.u >> 16) & 1u)) >> 16;
    return (ushort)r;
}
__device__ __forceinline__ float bf2f(unsigned u) {
    union { unsigned u; float f; } v; v.u = u << 16;
    return v.f;
}

// ---------------- Kernel 0: weight composition (fp32) ----------------
// W1s = Wsrc@Wa1 ; W1d = Wdst@Wa1 ; Wp1 = Wpos@Wa1 ; b1eff = bpos@Wa1 + ba1
__global__ __launch_bounds__(256) void compose_kernel(
    const float* __restrict__ Wsrc, const float* __restrict__ Wdst,
    const float* __restrict__ Wa1, const float* __restrict__ Wpos,
    const float* __restrict__ bpos, const float* __restrict__ ba1,
    float* __restrict__ W1s, float* __restrict__ W1d,
    float* __restrict__ Wp1, float* __restrict__ b1eff)
{
    __shared__ float a1[128 * 8]; // Wa1[:, j0..j0+8): [i][jl]
    const int t = threadIdx.x;
    const int j0 = blockIdx.x * 8;
    for (int idx = t; idx < 1024; idx += 256) {
        int i = idx >> 3, jl = idx & 7;
        a1[idx] = Wa1[i * 128 + j0 + jl];
    }
    __syncthreads();
    const int jl = t & 7, k0 = t >> 3; // k0: 0..31
#pragma unroll 1
    for (int kb = 0; kb < 4; ++kb) {
        int k = kb * 32 + k0;
        float s1 = 0.f, s2 = 0.f;
        for (int i = 0; i < 128; ++i) {
            float w = a1[i * 8 + jl];
            s1 = fmaf(Wsrc[k * 128 + i], w, s1);
            s2 = fmaf(Wdst[k * 128 + i], w, s2);
        }
        W1s[k * 128 + j0 + jl] = s1;
        W1d[k * 128 + j0 + jl] = s2;
    }
    if (t < 32) {
        int d = t >> 3, j = j0 + (t & 7);
        float s = 0.f;
        if (d < 3) {
            for (int i = 0; i < 128; ++i) s = fmaf(Wpos[d * 128 + i], a1[i * 8 + (t & 7)], s);
            Wp1[d * 128 + j] = s;
        } else {
            for (int i = 0; i < 128; ++i) s = fmaf(bpos[i], a1[i * 8 + (t & 7)], s);
            b1eff[j] = s + ba1[j];
        }
    }
}

// ---------------- Kernel 1: node GEMMs (MFMA, y selects) ----------------
// y=0: Ux(bf16) = x@W1s + pos@Wp1 + b1eff
// y=1: Vx(bf16) = x@W1d + pos@Wp1
// y=2: Xc(f32)  = x@W   - pos@Wpos
__global__ __launch_bounds__(256) void node_gemm(
    const float* __restrict__ x, const float* __restrict__ pos,
    const float* __restrict__ W, const float* __restrict__ W1s,
    const float* __restrict__ W1d, const float* __restrict__ Wpos,
    const float* __restrict__ Wp1, const float* __restrict__ b1eff,
    ushort* __restrict__ Ux, ushort* __restrict__ Vx, float* __restrict__ Xc)
{
    __shared__ ushort wsm[16384];
    const int t = threadIdx.x;
    const int w = t >> 6;
    const int l = t & 63;
    const int g = l >> 4;
    const int low = l & 15;
    const int y = blockIdx.y;
    const float* Wsel = (y == 0) ? W1s : (y == 1) ? W1d : W;
    const float* wps  = (y < 2) ? Wp1 : Wpos;

    for (int gi = t; gi < 2048; gi += 256) {
        int j = gi & 127, k8 = gi >> 7;
        short8 v;
#pragma unroll
        for (int i = 0; i < 8; ++i)
            v[i] = (short)f2bf(Wsel[(k8 * 8 + i) * 128 + j]);
        *(short8*)&wsm[j * 128 + ((k8 ^ (j & 15)) << 3)] = v;
    }
    float wp0[8], wp1v[8], wp2[8], bpv[8];
#pragma unroll
    for (int nb = 0; nb < 8; ++nb) {
        int ch = nb * 16 + low;
        wp0[nb] = wps[ch]; wp1v[nb] = wps[128 + ch]; wp2[nb] = wps[256 + ch];
        bpv[nb] = (y == 0) ? b1eff[ch] : 0.f;
    }
    __syncthreads();

    const int n0 = (blockIdx.x * 4 + w) * 16;
    if (n0 >= NN) return;
    const int rowi = min(n0 + low, NN - 1);

    short8 af[4];
#pragma unroll
    for (int kc = 0; kc < 4; ++kc) {
        const float* xp = x + (size_t)rowi * 128 + kc * 32 + g * 8;
        float4 a0 = *(const float4*)xp;
        float4 a1 = *(const float4*)(xp + 4);
        short8 v;
        v[0] = (short)f2bf(a0.x); v[1] = (short)f2bf(a0.y);
        v[2] = (short)f2bf(a0.z); v[3] = (short)f2bf(a0.w);
        v[4] = (short)f2bf(a1.x); v[5] = (short)f2bf(a1.y);
        v[6] = (short)f2bf(a1.z); v[7] = (short)f2bf(a1.w);
        af[kc] = v;
    }

    f32x4 acc[8];
#pragma unroll
    for (int nb = 0; nb < 8; ++nb) { acc[nb][0]=0.f; acc[nb][1]=0.f; acc[nb][2]=0.f; acc[nb][3]=0.f; }
#pragma unroll
    for (int nb = 0; nb < 8; ++nb) {
        int j = nb * 16 + low;
#pragma unroll
        for (int kc = 0; kc < 4; ++kc) {
            short8 bf = *(const short8*)&wsm[j * 128 + (((kc * 4 + g) ^ low) << 3)];
            acc[nb] = __builtin_amdgcn_mfma_f32_16x16x32_bf16(af[kc], bf, acc[nb], 0, 0, 0);
        }
    }

#pragma unroll
    for (int r = 0; r < 4; ++r) {
        int node = n0 + g * 4 + r;
        if (node >= NN) continue;
        float p0 = pos[node * 3], p1 = pos[node * 3 + 1], p2 = pos[node * 3 + 2];
#pragma unroll
        for (int nb = 0; nb < 8; ++nb) {
            float pterm = p0 * wp0[nb] + p1 * wp1v[nb] + p2 * wp2[nb];
            size_t idx = (size_t)node * 128 + nb * 16 + low;
            if (y == 0)      Ux[idx] = f2bf(acc[nb][r] + pterm + bpv[nb]);
            else if (y == 1) Vx[idx] = f2bf(acc[nb][r] + pterm);
            else             Xc[idx] = acc[nb][r] - pterm;
        }
    }
}

// ---------------- CSR build ----------------
__global__ __launch_bounds__(256) void hist_kernel(const int* __restrict__ ei, int* __restrict__ counts)
{
    int e = blockIdx.x * 256 + threadIdx.x;
    if (e < NE) atomicAdd(&counts[ei[2 * e]], 1);
}

__global__ __launch_bounds__(1024) void scan_kernel(const int* __restrict__ counts,
                                                    int* __restrict__ offsets, int* __restrict__ cursor)
{
    __shared__ int sums[1024];
    const int t = threadIdx.x;
    const int C = (NN + 1023) / 1024;
    int lo = t * C, hi = min(lo + C, NN);
    int s = 0;
    for (int i = lo; i < hi; ++i) s += counts[i];
    sums[t] = s;
    __syncthreads();
    for (int d = 1; d < 1024; d <<= 1) {
        int v = (t >= d) ? sums[t - d] : 0;
        __syncthreads();
        sums[t] += v;
        __syncthreads();
    }
    int run = (t == 0) ? 0 : sums[t - 1];
    for (int i = lo; i < hi; ++i) {
        offsets[i] = run;
        cursor[i] = run;
        run += counts[i];
    }
    if (t == 1023) offsets[NN] = sums[1023];
}

__global__ __launch_bounds__(256) void scatter_kernel(const int* __restrict__ ei,
                                                      int* __restrict__ cursor,
                                                      int* __restrict__ rowc, int* __restrict__ colc)
{
    int e = blockIdx.x * 256 + threadIdx.x;
    if (e < NE) {
        int r = ei[2 * e];
        int c = ei[2 * e + 1];
        int p = atomicAdd(&cursor[r], 1);
        rowc[p] = r;
        colc[p] = c;
    }
}

// ---------------- Pass A: expalpha = exp(relu(Ux[r]-Vx[c])@W2 + b2), packed (ch,ch+64) ----------------
__global__ __launch_bounds__(256) void expalpha_kernel(
    const ushort* __restrict__ Ux, const ushort* __restrict__ Vx,
    const float* __restrict__ Wa2, const float* __restrict__ ba2,
    const int* __restrict__ rowc, const int* __restrict__ colc,
    unsigned* __restrict__ expW)
{
    __shared__ ushort wl[16384];

    const int t = threadIdx.x;
    const int w = t >> 6;
    const int l = t & 63;
    const int g = l >> 4;
    const int low = l & 15;

    for (int gi = t; gi < 2048; gi += 256) {
        int j = gi & 127, k8 = gi >> 7;
        short8 v;
#pragma unroll
        for (int i = 0; i < 8; ++i)
            v[i] = (short)f2bf(Wa2[(k8 * 8 + i) * 128 + j]);
        *(short8*)&wl[j * 128 + ((k8 ^ (j & 15)) << 3)] = v;
    }
    float b2v[8];
#pragma unroll
    for (int nb = 0; nb < 8; ++nb) b2v[nb] = ba2[nb * 16 + low];
    __syncthreads();

    const int nw = gridDim.x * 4;
    const int w0 = blockIdx.x * 4 + w;

    for (int t0 = w0; t0 < NTILES; t0 += 2 * nw) {
        const int t1 = t0 + nw;
        const bool has1 = t1 < NTILES;

        short8 hfA[4], hfB[4];
        {
            int slot = t0 * 16 + low;
            int r = rowc[slot], c = colc[slot];
            const ushort* up = Ux + (size_t)r * 128 + g * 8;
            const ushort* vp = Vx + (size_t)c * 128 + g * 8;
#pragma unroll
            for (int kc = 0; kc < 4; ++kc) {
                short8 uu = *(const short8*)(up + kc * 32);
                short8 vv = *(const short8*)(vp + kc * 32);
                short8 h;
#pragma unroll
                for (int i = 0; i < 8; ++i)
                    h[i] = (short)f2bf(fmaxf(bf2f((ushort)uu[i]) - bf2f((ushort)vv[i]), 0.f));
                hfA[kc] = h;
            }
        }
        if (has1) {
            int slot = t1 * 16 + low;
            int r = rowc[slot], c = colc[slot];
            const ushort* up = Ux + (size_t)r * 128 + g * 8;
            const ushort* vp = Vx + (size_t)c * 128 + g * 8;
#pragma unroll
            for (int kc = 0; kc < 4; ++kc) {
                short8 uu = *(const short8*)(up + kc * 32);
                short8 vv = *(const short8*)(vp + kc * 32);
                short8 h;
#pragma unroll
                for (int i = 0; i < 8; ++i)
                    h[i] = (short)f2bf(fmaxf(bf2f((ushort)uu[i]) - bf2f((ushort)vv[i]), 0.f));
                hfB[kc] = h;
            }
        }

        f32x4 accA[8], accB[8];
#pragma unroll
        for (int nb = 0; nb < 8; ++nb) {
            accA[nb][0]=0.f; accA[nb][1]=0.f; accA[nb][2]=0.f; accA[nb][3]=0.f;
            accB[nb][0]=0.f; accB[nb][1]=0.f; accB[nb][2]=0.f; accB[nb][3]=0.f;
        }
#pragma unroll
        for (int nb = 0; nb < 8; ++nb) {
            int j = nb * 16 + low;
#pragma unroll
            for (int kc = 0; kc < 4; ++kc) {
                short8 bf = *(const short8*)&wl[j * 128 + (((kc * 4 + g) ^ low) << 3)];
                accA[nb] = __builtin_amdgcn_mfma_f32_16x16x32_bf16(hfA[kc], bf, accA[nb], 0, 0, 0);
                if (has1)
                    accB[nb] = __builtin_amdgcn_mfma_f32_16x16x32_bf16(hfB[kc], bf, accB[nb], 0, 0, 0);
            }
        }

        // exp + pack channels (ch, ch+64) into one dword, store
#pragma unroll
        for (int nb = 0; nb < 4; ++nb) {
#pragma unroll
            for (int r = 0; r < 4; ++r) {
                float e0 = __expf(accA[nb][r] + b2v[nb]);
                float e1 = __expf(accA[nb + 4][r] + b2v[nb + 4]);
                expW[(size_t)(t0 * 16 + g * 4 + r) * 64 + nb * 16 + low] =
                    (unsigned)f2bf(e0) | ((unsigned)f2bf(e1) << 16);
                if (has1) {
                    float f0 = __expf(accB[nb][r] + b2v[nb]);
                    float f1 = __expf(accB[nb + 4][r] + b2v[nb + 4]);
                    expW[(size_t)(t1 * 16 + g * 4 + r) * 64 + nb * 16 + low] =
                        (unsigned)f2bf(f0) | ((unsigned)f2bf(f1) << 16);
                }
            }
        }
    }
}

// ---------------- Pass B: single-pass per-node weighted aggregate ----------------
__global__ __launch_bounds__(256) void aggregate_kernel(
    const float* __restrict__ pos,
    const float* __restrict__ Wpos, const float* __restrict__ bpos,
    const float* __restrict__ Xc,
    const int* __restrict__ offsets, const int* __restrict__ colc,
    const unsigned* __restrict__ expW, float* __restrict__ out)
{
    const int l = threadIdx.x & 63;
    const int wid = blockIdx.x * 4 + (threadIdx.x >> 6);
    const int nw = gridDim.x * 4;

    const float wpa0 = Wpos[l], wpa1 = Wpos[128 + l], wpa2 = Wpos[256 + l];
    const float wpb0 = Wpos[64 + l], wpb1 = Wpos[192 + l], wpb2 = Wpos[320 + l];
    const float bpa = bpos[l], bpb = bpos[64 + l];

    for (int node = wid; node < NN; node += nw) {
        const int aoff = offsets[node];
        const int deg = offsets[node + 1] - aoff;
        const unsigned* ap = expW + (size_t)aoff * 64 + l;

        float s0 = 0.f, s1 = 0.f, o0 = 0.f, o1 = 0.f;
#pragma unroll 2
        for (int e = 0; e < deg; ++e) {
            unsigned v = ap[(size_t)e * 64];
            int c = colc[aoff + e];
            float w0 = bf2f(v & 0xffffu);
            float w1 = bf2f(v >> 16);
            float xc0 = Xc[(size_t)c * 128 + l];
            float xc1 = Xc[(size_t)c * 128 + l + 64];
            s0 += w0; o0 = fmaf(w0, xc0, o0);
            s1 += w1; o1 = fmaf(w1, xc1, o1);
        }
        float p0 = pos[node * 3], p1 = pos[node * 3 + 1], p2 = pos[node * 3 + 2];
        float pb0 = bpa + p0 * wpa0 + p1 * wpa1 + p2 * wpa2;
        float pb1 = bpb + p0 * wpb0 + p1 * wpb1 + p2 * wpb2;
        out[(size_t)node * 128 + l]      = (o0 + pb0 * s0) / (s0 + EPSV);
        out[(size_t)node * 128 + l + 64] = (o1 + pb1 * s1) / (s1 + EPSV);
    }
}

extern "C" void kernel_launch(void* const* d_in, const int* in_sizes, int n_in,
                              void* d_out, int out_size, void* d_ws, size_t ws_size,
                              hipStream_t stream)
{
    const float* x    = (const float*)d_in[0];
    const float* pos  = (const float*)d_in[1];
    const int*   ei   = (const int*)d_in[2];
    const float* W    = (const float*)d_in[3];
    const float* Wsrc = (const float*)d_in[4];
    const float* Wdst = (const float*)d_in[5];
    const float* Wpos = (const float*)d_in[6];
    const float* bpos = (const float*)d_in[7];
    const float* Wa1  = (const float*)d_in[8];
    const float* ba1  = (const float*)d_in[9];
    const float* Wa2  = (const float*)d_in[10];
    const float* ba2  = (const float*)d_in[11];
    float* out = (float*)d_out;

    // ws layout: Ux/Vx bf16 (25.6MB) + Xc f32 (25.6MB) + composed weights + CSR + expW (128MB) ~= 184MB
    ushort* Ux = (ushort*)d_ws;
    ushort* Vx = Ux + (size_t)NN * DD;
    float*  Xc = (float*)(Vx + (size_t)NN * DD);
    float* W1s = Xc + (size_t)NN * DD;
    float* W1d = W1s + 128 * 128;
    float* Wp1 = W1d + 128 * 128;
    float* b1eff = Wp1 + 384;
    int* offsets = (int*)(b1eff + 128);
    int* cursor  = offsets + (NN + 1);
    int* counts  = cursor + NN;
    int* rowc    = counts + NN;
    int* colc    = rowc + NE;
    unsigned* expW = (unsigned*)(colc + NE);

    compose_kernel<<<16, 256, 0, stream>>>(Wsrc, Wdst, Wa1, Wpos, bpos, ba1, W1s, W1d, Wp1, b1eff);
    node_gemm<<<dim3((NN + 63) / 64, 3), 256, 0, stream>>>(
        x, pos, W, W1s, W1d, Wpos, Wp1, b1eff, Ux, Vx, Xc);
    hipMemsetAsync(counts, 0, NN * sizeof(int), stream);
    hist_kernel<<<(NE + 255) / 256, 256, 0, stream>>>(ei, counts);
    scan_kernel<<<1, 1024, 0, stream>>>(counts, offsets, cursor);
    scatter_kernel<<<(NE + 255) / 256, 256, 0, stream>>>(ei, cursor, rowc, colc);
    expalpha_kernel<<<1024, 256, 0, stream>>>(Ux, Vx, Wa2, ba2, rowc, colc, expW);
    aggregate_kernel<<<4096, 256, 0, stream>>>(pos, Wpos, bpos, Xc, offsets, colc, expW, out);
}